// Round 10
// baseline (523.247 us; speedup 1.0000x reference)
//
#include <hip/hip_runtime.h>
#include <hip/hip_bf16.h>

#define SEQ 2048
#define DM 2048
#define NH 16
#define NKV 4
#define HD 128

typedef float f32x4 __attribute__((ext_vector_type(4)));
typedef short s16x8 __attribute__((ext_vector_type(8)));
typedef short s16x4 __attribute__((ext_vector_type(4)));

__device__ inline __hip_bfloat16 f2b(float f) { return __float2bfloat16(f); }
__device__ inline float b2f_us(unsigned short u) { return __uint_as_float(((unsigned)u) << 16); }
__device__ inline short f2b_s(float f) {
    __hip_bfloat16 h = __float2bfloat16(f);
    return *(short*)&h;
}

// async global->LDS, 16B per lane; HW dest = wave-uniform base + lane*16.
__device__ inline void gl_lds16(const void* g, void* l) {
    __builtin_amdgcn_global_load_lds((const __attribute__((address_space(1))) void*)g,
                                     (__attribute__((address_space(3))) void*)l, 16, 0, 0);
}

// ---------------- fused prep: cast x->bf16  +  4x transpose_cast (weights) ----------
__global__ void prep_kernel(const float* __restrict__ x,
                            const float* __restrict__ wq, const float* __restrict__ wk,
                            const float* __restrict__ wv, const float* __restrict__ wo,
                            __hip_bfloat16* __restrict__ xb,
                            __hip_bfloat16* __restrict__ wqkvt,
                            __hip_bfloat16* __restrict__ wot) {
    __shared__ float tile[32][33];
    int bid = blockIdx.x;
    const int t = threadIdx.x;
    if (bid < 8192) {
        int i = (bid * 256 + t) * 4;
        float4 v = *(const float4*)(x + i);
        __hip_bfloat16 o4[4] = {f2b(v.x), f2b(v.y), f2b(v.z), f2b(v.w)};
        *(ushort4*)(xb + i) = *(ushort4*)o4;
        return;
    }
    bid -= 8192;
    const float* in;
    __hip_bfloat16* out;
    int N, bx, by;
    if (bid < 4096) {
        in = wq; out = wqkvt; N = 2048; bx = bid & 63; by = bid >> 6;
    } else if (bid < 5120) {
        bid -= 4096; in = wk; out = wqkvt + (size_t)2048 * 2048; N = 512; bx = bid & 15; by = bid >> 4;
    } else if (bid < 6144) {
        bid -= 5120; in = wv; out = wqkvt + (size_t)2560 * 2048; N = 512; bx = bid & 15; by = bid >> 4;
    } else {
        bid -= 6144; in = wo; out = wot; N = 2048; bx = bid & 63; by = bid >> 6;
    }
    const int K = 2048;
    int n0 = bx * 32, k0 = by * 32;
    int tx = t & 31, ty = t >> 5; // logical (32,8)
    for (int r = ty; r < 32; r += 8)
        tile[r][tx] = in[(size_t)(k0 + r) * N + n0 + tx];
    __syncthreads();
    for (int r = ty; r < 32; r += 8)
        out[(size_t)(n0 + r) * K + k0 + tx] = f2b(tile[tx][r]);
}

// ---------------- GEMM: C[M][N] = A[M][Kd] * Bt[N][Kd]^T ----------------
// m97 structure + GROUP_M=8 grouped supertile swizzle (128^2 fits shapes exactly).
template <int OUT_F32>
__global__ __launch_bounds__(256, 3) void gemm_bt(
    const __hip_bfloat16* __restrict__ A,
    const __hip_bfloat16* __restrict__ Bt,
    void* __restrict__ Cp, int M, int N, int Kd) {
    __shared__ __hip_bfloat16 As[128 * 64]; // [row][64], swizzled 16B slots
    __shared__ __hip_bfloat16 Bs[128 * 64];
    const int nx = gridDim.x, ny = gridDim.y;
    const int pid = blockIdx.y * nx + blockIdx.x;
    const int GM = 8;
    const int grp = pid / (GM * nx);
    const int first = grp * GM;
    const int gsz = (ny - first < GM) ? (ny - first) : GM;
    const int mt = first + (pid % gsz);
    const int ntile = (pid % (GM * nx)) / gsz;
    const int m0 = mt * 128, n0 = ntile * 128;

    const int t = threadIdx.x;
    const int wv = t >> 6, lane = t & 63;
    const int wm = (wv >> 1) * 64, wn = (wv & 1) * 64;
    const int lrow = lane & 15, quad = lane >> 4;
    f32x4 acc[4][4];
    f32x4 z4 = {0.f, 0.f, 0.f, 0.f};
    for (int i = 0; i < 4; ++i)
        for (int j = 0; j < 4; ++j) acc[i][j] = z4;

    for (int k0 = 0; k0 < Kd; k0 += 64) {
        __syncthreads();
        for (int i = 0; i < 4; ++i) {
            int flat = i * 256 + t;          // 16B slot id
            int row = flat >> 3;
            int cb = (flat & 7) ^ (row & 7); // logical 16B-block for this slot
            gl_lds16(A + (size_t)(m0 + row) * Kd + k0 + cb * 8, &As[flat * 8]);
            gl_lds16(Bt + (size_t)(n0 + row) * Kd + k0 + cb * 8, &Bs[flat * 8]);
        }
        __syncthreads();
        for (int kk = 0; kk < 2; ++kk) {
            s16x8 af[4], bf[4];
            for (int i = 0; i < 4; ++i) {
                int ra = wm + i * 16 + lrow;
                int rb = wn + i * 16 + lrow;
                int pba = ((kk * 4 + quad) ^ (ra & 7)) * 8;
                int pbb = ((kk * 4 + quad) ^ (rb & 7)) * 8;
                af[i] = *(const s16x8*)&As[ra * 64 + pba];
                bf[i] = *(const s16x8*)&Bs[rb * 64 + pbb];
            }
            for (int i = 0; i < 4; ++i)
                for (int j = 0; j < 4; ++j)
                    acc[i][j] = __builtin_amdgcn_mfma_f32_16x16x32_bf16(af[i], bf[j],
                                                                        acc[i][j], 0, 0, 0);
        }
    }
    for (int i = 0; i < 4; ++i)
        for (int j = 0; j < 4; ++j)
            for (int r = 0; r < 4; ++r) {
                int m = m0 + wm + i * 16 + quad * 4 + r;
                int n = n0 + wn + j * 16 + lrow;
                if (OUT_F32)
                    ((float*)Cp)[(size_t)m * N + n] = acc[i][j][r];
                else
                    ((__hip_bfloat16*)Cp)[(size_t)m * N + n] = f2b(acc[i][j][r]);
            }
}

// ---------------- fused RoPE(q,k) + V-transpose ----------------
#define QSC 0.12751744f /* (1/sqrt(128)) * 1.4426950408889634 */
__global__ void rv_kernel(const __hip_bfloat16* __restrict__ qkv,
                          const float* __restrict__ fcos, const float* __restrict__ fsin,
                          __hip_bfloat16* __restrict__ q, __hip_bfloat16* __restrict__ k,
                          __hip_bfloat16* __restrict__ vt) {
    __shared__ __hip_bfloat16 tile[128][136];
    const int t = threadIdx.x;
    if (blockIdx.x < 4096) {
        int tok = blockIdx.x; // b*SEQ + s
        int b = tok >> 11, s = tok & 2047;
        const __hip_bfloat16* row = qkv + (size_t)tok * 3072;
        for (int it = t; it < 320; it += 256) { // 2560 elems / 8
            int col = it * 8;
            s16x8 v = *(const s16x8*)(row + col);
            int p0 = (col & 127) >> 1;
            f32x4 c4 = *(const f32x4*)(fcos + s * 64 + p0);
            f32x4 s4 = *(const f32x4*)(fsin + s * 64 + p0);
            float scl = (col < 2048) ? QSC : 1.0f;
            short outv[8];
            for (int p = 0; p < 4; ++p) {
                float x0 = b2f_us((unsigned short)v[2 * p]);
                float x1 = b2f_us((unsigned short)v[2 * p + 1]);
                outv[2 * p] = f2b_s((x0 * c4[p] - x1 * s4[p]) * scl);
                outv[2 * p + 1] = f2b_s((x0 * s4[p] + x1 * c4[p]) * scl);
            }
            int d = col & 127;
            if (col < 2048) {
                int h = col >> 7;
                *(s16x8*)(q + ((size_t)((b * NH + h) * SEQ + s)) * HD + d) = *(s16x8*)outv;
            } else {
                int h = (col - 2048) >> 7;
                *(s16x8*)(k + ((size_t)((b * NKV + h) * SEQ + s)) * HD + d) = *(s16x8*)outv;
            }
        }
        return;
    }
    int r = blockIdx.x - 4096;
    int s0 = (r & 15) * 128;
    int bh = r >> 4; // b*NKV + kvh
    int b = bh >> 2, kvh = bh & 3;
    for (int i = 0; i < 8; ++i) {
        int flat = (i * 256 + t) * 8;
        int row = flat >> 7, col = flat & 127;
        *(s16x8*)&tile[row][col] =
            *(const s16x8*)(qkv + (size_t)(b * SEQ + s0 + row) * 3072 + 2560 + kvh * 128 + col);
    }
    __syncthreads();
    for (int i = 0; i < 8; ++i) {
        int dd = i * 16 + (t >> 4);
        int ss = (t & 15) * 8;
        __hip_bfloat16 tmp[8];
        for (int j = 0; j < 8; ++j) tmp[j] = tile[ss + j][dd];
        *(s16x8*)(vt + ((size_t)((b * NKV + kvh) * HD + dd)) * SEQ + s0 + ss) = *(s16x8*)tmp;
    }
}

// ---------------- causal flash attention (GQA), K-SPLIT, 64 q-rows / 512 threads ------
// R17: every config R8-R16 landed at ~52% of its occupancy cap with all pipes <40%
// -> latency-bound; the only unexploited lever is TOTAL wave count. K-split: 8 waves =
// 4 row-groups (16 rows, proven R15 inner) x 2 key-halves. A-half: tiles [0,bx];
// B-half: tiles [bx+1, Tg). Grid (32,32) = 1024 blocks x 8 waves = 8192 waves =
// 32/CU = 100% occupancy cap (vs 16 before). Enablers: KVBLK=32 (barrier count/wave
// unchanged: half-size x half-count; LDS-reads/key invariant; ~5% less masked MFMA);
// K staged via global_load_lds w/ XOR-swizzled source (no kr regs; 2-way bank reads);
// V reg-staged w/ posOf permute (16 regs); LDS 34,816B -> 4 blocks/CU; VGPR target
// <=64 (R15 measured 60 with MORE staging regs). End merge: B writes {m,l,accO}
// (34 f32/lane) into freed K/V LDS (exactly 34,816B), A combines + writes O.
__global__ __launch_bounds__(512, 4) void attn_kernel(
    const __hip_bfloat16* __restrict__ q, const __hip_bfloat16* __restrict__ k,
    const __hip_bfloat16* __restrict__ vt, __hip_bfloat16* __restrict__ o) {
    __shared__ __attribute__((aligned(16))) char smem[34816];
    __hip_bfloat16* KsA = (__hip_bfloat16*)smem;   // [32 keys][128 d], swizzled 16B blks
    __hip_bfloat16* KsB = KsA + 32 * 128;
    __hip_bfloat16* VsA = KsB + 32 * 128;          // [128 d][36], posOf-permuted keys
    __hip_bfloat16* VsB = VsA + 128 * 36;
    float* mrg = (float*)smem;                     // merge overlay: 4*64*34 = 8704 f32

    const int bh = blockIdx.y;
    const int bx = (bh < 16) ? (int)(gridDim.x - 1 - blockIdx.x) : (int)blockIdx.x;
    const int b = bh >> 4, h = bh & 15;
    const int kvh = h >> 2;
    const int t = threadIdx.x;
    const int w = t >> 6, lane = t & 63;
    const int g = w & 3, half = w >> 2;
    const int lrow = lane & 15, quad = lane >> 4;
    const int q0 = bx * 64;
    const int qrow = q0 + g * 16 + lrow; // this lane's ONE q row
    const int Tg = 2 * bx + 1 + (g >> 1); // total key tiles this group needs

    // Q fragments, B-operand role: n=qrow (lrow), k=d (quad*8+j). Pre-scaled in rope.
    const __hip_bfloat16* qp = q + ((size_t)((b * NH + h) * SEQ + qrow)) * HD;
    s16x8 qf[4];
    for (int ks = 0; ks < 4; ++ks) qf[ks] = *(const s16x8*)(qp + ks * 32 + quad * 8);

    float m_i = -1e30f, l_i = 0.f;
    f32x4 accO[8];
    f32x4 z4 = {0.f, 0.f, 0.f, 0.f};
    for (int d = 0; d < 8; ++d) accO[d] = z4;

    const __hip_bfloat16* kbase = k + ((size_t)(b * NKV + kvh) * SEQ) * HD;
    const __hip_bfloat16* vbase = vt + ((size_t)(b * NKV + kvh) * HD) * SEQ;

    // K tile kt -> Ks (unpadded, 16B-block XOR swizzle): slot (row, pblk) holds
    // logical block pblk ^ (row&7). One gl_lds per thread per tile.
    auto issue_k = [&](int kt, __hip_bfloat16* dst) {
        const __hip_bfloat16* src = kbase + (size_t)(kt * 32 + (t >> 4)) * HD +
                                    (((t & 15) ^ ((t >> 4) & 7)) << 3);
        gl_lds16(src, dst + t * 8);
    };
    s16x8 vr[2]; // V staging: one s16x8 per tile per thread
    auto load_v = [&](int ka, int kb) {
        int row = t >> 2, k0 = (t & 3) * 8;
        vr[0] = *(const s16x8*)(vbase + (size_t)row * SEQ + ka * 32 + k0);
        vr[1] = *(const s16x8*)(vbase + (size_t)row * SEQ + kb * 32 + k0);
    };
    auto store_v = [&]() {
        int row = t >> 2, k0 = (t & 3) * 8;
        // posOf within 32-key tile: keys k0..k0+3 -> pb..pb+3; k0+4..k0+7 -> pb+8..11
        int pb = (((k0 >> 2) & 3) << 3) | (((k0 >> 4) & 1) << 2);
        s16x4 lo0 = {vr[0][0], vr[0][1], vr[0][2], vr[0][3]};
        s16x4 hi0 = {vr[0][4], vr[0][5], vr[0][6], vr[0][7]};
        s16x4 lo1 = {vr[1][0], vr[1][1], vr[1][2], vr[1][3]};
        s16x4 hi1 = {vr[1][4], vr[1][5], vr[1][6], vr[1][7]};
        *(s16x4*)&VsA[row * 36 + pb] = lo0;
        *(s16x4*)&VsA[row * 36 + pb + 8] = hi0;
        *(s16x4*)&VsB[row * 36 + pb] = lo1;
        *(s16x4*)&VsB[row * 36 + pb + 8] = hi1;
    };

    issue_k(0, KsA);
    issue_k(bx + 1, KsB);
    load_v(0, bx + 1);
    store_v();

    for (int s = 0; s <= bx; ++s) {
        __syncthreads(); // vmcnt(0): K tiles landed; V stores visible
        const bool more = s < bx;
        if (more) load_v(s + 1, bx + s + 2); // reg prefetch, hidden under compute

        const int kt = half ? (bx + 1 + s) : s;
        const bool active = half ? (bx + 1 + s < Tg) : true;
        if (active) {
            const __hip_bfloat16* Ksm = half ? KsB : KsA;
            const __hip_bfloat16* Vsm = half ? VsB : VsA;
            const bool mtile = (kt * 32 + 31 > q0 + g * 16);
            float sv[2][4];
            __builtin_amdgcn_s_setprio(1);
            for (int nt = 0; nt < 2; ++nt) {
                f32x4 sacc = z4;
                for (int ks = 0; ks < 4; ++ks) {
                    s16x8 kf = *(const s16x8*)&Ksm[(nt * 16 + lrow) * 128 +
                                                   (((ks * 4 + quad) ^ (lrow & 7)) << 3)];
                    sacc = __builtin_amdgcn_mfma_f32_16x16x32_bf16(kf, qf[ks], sacc, 0, 0, 0);
                }
                if (mtile) {
                    for (int r = 0; r < 4; ++r) {
                        int key = kt * 32 + nt * 16 + quad * 4 + r;
                        sv[nt][r] = (key > qrow) ? -1e30f : sacc[r];
                    }
                } else {
                    for (int r = 0; r < 4; ++r) sv[nt][r] = sacc[r];
                }
            }
            __builtin_amdgcn_s_setprio(0);
            float mt2 = fmaxf(fmaxf(fmaxf(sv[0][0], sv[0][1]), fmaxf(sv[0][2], sv[0][3])),
                              fmaxf(fmaxf(sv[1][0], sv[1][1]), fmaxf(sv[1][2], sv[1][3])));
            mt2 = fmaxf(mt2, __shfl_xor(mt2, 16, 64));
            mt2 = fmaxf(mt2, __shfl_xor(mt2, 32, 64));
            // defer-max (exp2 domain): deferred p bounded by 2^8.
            if (!__all(mt2 <= m_i + 8.f)) {
                float mn = fmaxf(m_i, mt2);
                float alpha = exp2f(m_i - mn);
                l_i *= alpha;
                for (int d = 0; d < 8; ++d)
                    for (int r = 0; r < 4; ++r) accO[d][r] *= alpha;
                m_i = mn;
            }
            // P in-register; k-slot (quad,j) <-> key (j>>2)*16 + quad*4 + (j&3).
            float rs = 0.f;
            s16x8 pf;
#pragma unroll
            for (int j = 0; j < 8; ++j) {
                float p = exp2f(sv[j >> 2][j & 3] - m_i);
                rs += p;
                pf[j] = f2b_s(p);
            }
            rs += __shfl_xor(rs, 16, 64);
            rs += __shfl_xor(rs, 32, 64);
            l_i += rs;
            __builtin_amdgcn_s_setprio(1);
            for (int dt = 0; dt < 8; ++dt) {
                s16x8 vf = *(const s16x8*)&Vsm[(dt * 16 + lrow) * 36 + quad * 8];
                accO[dt] = __builtin_amdgcn_mfma_f32_16x16x32_bf16(vf, pf, accO[dt], 0, 0, 0);
            }
            __builtin_amdgcn_s_setprio(0);
        }

        __syncthreads(); // all waves done reading Ks/Vs
        if (more) {
            issue_k(s + 1, KsA);          // bufs free; drained at next top barrier
            issue_k(bx + s + 2, KsB);
            store_v();
        }
    }

    // ---- merge A/B halves (LDS now free; overlay mrg spans the whole smem) ----
    if (half == 1) {
        float* p = mrg + (size_t)(g * 64 + lane) * 34;
        p[0] = m_i;
        p[1] = l_i;
        for (int dt = 0; dt < 8; ++dt)
            for (int r = 0; r < 4; ++r) p[2 + dt * 4 + r] = accO[dt][r];
    }
    __syncthreads();
    if (half == 0) {
        float* p = mrg + (size_t)(g * 64 + lane) * 34;
        float mB = p[0], lB = p[1];
        float mS = fmaxf(m_i, mB);
        float eA = exp2f(m_i - mS);
        float eB = exp2f(mB - mS);
        float inv = 1.0f / (l_i * eA + lB * eB);
        __hip_bfloat16* op = o + (size_t)(b * SEQ + qrow) * DM + h * HD;
        for (int dt = 0; dt < 8; ++dt) {
            short ov[4];
            for (int r = 0; r < 4; ++r)
                ov[r] = f2b_s((accO[dt][r] * eA + p[2 + dt * 4 + r] * eB) * inv);
            *(s16x4*)(op + dt * 16 + quad * 4) = *(s16x4*)ov;
        }
    }
}

extern "C" void kernel_launch(void* const* d_in, const int* in_sizes, int n_in,
                              void* d_out, int out_size, void* d_ws, size_t ws_size,
                              hipStream_t stream) {
    (void)in_sizes; (void)n_in; (void)out_size; (void)ws_size;
    const float* x  = (const float*)d_in[0];
    const float* fc = (const float*)d_in[1];
    const float* fs = (const float*)d_in[2];
    // d_in[3] = mask: exactly causal, applied analytically
    const float* wq = (const float*)d_in[4];
    const float* wk = (const float*)d_in[5];
    const float* wv = (const float*)d_in[6];
    const float* wo = (const float*)d_in[7];

    __hip_bfloat16* xb    = (__hip_bfloat16*)d_ws;            // [4096][2048]
    __hip_bfloat16* wqkvt = xb + (size_t)8388608;             // [3072][2048]
    __hip_bfloat16* wot   = wqkvt + (size_t)6291456;          // [2048][2048]
    __hip_bfloat16* qkv   = wot + (size_t)4194304;            // [4096][3072]
    __hip_bfloat16* qb    = xb;                               // aliases xb
    __hip_bfloat16* kb    = wqkvt;                            // aliases wqkvt
    __hip_bfloat16* vtb   = wqkvt + (size_t)2097152;
    __hip_bfloat16* attno = qkv;                              // aliases qkv

    prep_kernel<<<18432, 256, 0, stream>>>(x, wq, wk, wv, wo, xb, wqkvt, wot);
    gemm_bt<0><<<dim3(24, 32), 256, 0, stream>>>(xb, wqkvt, qkv, 4096, 3072, 2048);
    rv_kernel<<<4224, 256, 0, stream>>>(qkv, fc, fs, qb, kb, vtb);
    attn_kernel<<<dim3(32, 32), 512, 0, stream>>>(qb, kb, vtb, attno);
    gemm_bt<1><<<dim3(16, 32), 256, 0, stream>>>(attno, wot, d_out, 4096, 2048, 2048);
}

// Round 11
// 323.689 us; speedup vs baseline: 1.6165x; 1.6165x over previous
//
#include <hip/hip_runtime.h>
#include <hip/hip_bf16.h>

#define SEQ 2048
#define DM 2048
#define NH 16
#define NKV 4
#define HD 128

typedef float f32x4 __attribute__((ext_vector_type(4)));
typedef short s16x8 __attribute__((ext_vector_type(8)));
typedef short s16x4 __attribute__((ext_vector_type(4)));

__device__ inline __hip_bfloat16 f2b(float f) { return __float2bfloat16(f); }
__device__ inline float b2f_us(unsigned short u) { return __uint_as_float(((unsigned)u) << 16); }
__device__ inline short f2b_s(float f) {
    __hip_bfloat16 h = __float2bfloat16(f);
    return *(short*)&h;
}

// async global->LDS, 16B per lane; HW dest = wave-uniform base + lane*16.
__device__ inline void gl_lds16(const void* g, void* l) {
    __builtin_amdgcn_global_load_lds((const __attribute__((address_space(1))) void*)g,
                                     (__attribute__((address_space(3))) void*)l, 16, 0, 0);
}

// ---------------- cast fp32 -> bf16 ----------------
__global__ void cast_kernel(const float* __restrict__ in, __hip_bfloat16* __restrict__ out, int n) {
    int i = (blockIdx.x * 256 + threadIdx.x) * 4;
    if (i < n) {
        float4 v = *(const float4*)(in + i);
        __hip_bfloat16 o4[4] = {f2b(v.x), f2b(v.y), f2b(v.z), f2b(v.w)};
        *(ushort4*)(out + i) = *(ushort4*)o4;
    }
}

// ---------------- transpose + cast: in[K][N] fp32 -> out[N][K] bf16 ----------------
__global__ void transpose_cast(const float* __restrict__ in, __hip_bfloat16* __restrict__ out,
                               int K, int N) {
    __shared__ float tile[32][33];
    int n0 = blockIdx.x * 32, k0 = blockIdx.y * 32;
    int tx = threadIdx.x, ty = threadIdx.y; // block (32,8)
    for (int r = ty; r < 32; r += 8)
        tile[r][tx] = in[(size_t)(k0 + r) * N + n0 + tx];
    __syncthreads();
    for (int r = ty; r < 32; r += 8)
        out[(size_t)(n0 + r) * K + k0 + tx] = f2b(tile[tx][r]);
}

// ---------------- GEMM: C[M][N] = A[M][Kd] * Bt[N][Kd]^T ----------------
// m97 structure + GROUP_M=8 grouped supertile swizzle. 128^2 tile fits the shapes
// exactly: 768 blocks = 3/CU (gemm1) and 512 = 2/CU (gemm2). The 256^2 counted-vmcnt
// experiment (R14) regressed (underfilled grid + coarse 1-phase interleave).
template <int OUT_F32>
__global__ __launch_bounds__(256, 3) void gemm_bt(
    const __hip_bfloat16* __restrict__ A,
    const __hip_bfloat16* __restrict__ Bt,
    void* __restrict__ Cp, int M, int N, int Kd) {
    __shared__ __hip_bfloat16 As[128 * 64]; // [row][64], swizzled 16B slots
    __shared__ __hip_bfloat16 Bs[128 * 64];
    const int nx = gridDim.x, ny = gridDim.y;
    const int pid = blockIdx.y * nx + blockIdx.x;
    const int GM = 8;
    const int grp = pid / (GM * nx);
    const int first = grp * GM;
    const int gsz = (ny - first < GM) ? (ny - first) : GM;
    const int mt = first + (pid % gsz);
    const int ntile = (pid % (GM * nx)) / gsz;
    const int m0 = mt * 128, n0 = ntile * 128;

    const int t = threadIdx.x;
    const int wv = t >> 6, lane = t & 63;
    const int wm = (wv >> 1) * 64, wn = (wv & 1) * 64;
    const int lrow = lane & 15, quad = lane >> 4;
    f32x4 acc[4][4];
    f32x4 z4 = {0.f, 0.f, 0.f, 0.f};
    for (int i = 0; i < 4; ++i)
        for (int j = 0; j < 4; ++j) acc[i][j] = z4;

    for (int k0 = 0; k0 < Kd; k0 += 64) {
        __syncthreads();
        for (int i = 0; i < 4; ++i) {
            int flat = i * 256 + t;          // 16B slot id
            int row = flat >> 3;
            int cb = (flat & 7) ^ (row & 7); // logical 16B-block for this slot
            gl_lds16(A + (size_t)(m0 + row) * Kd + k0 + cb * 8, &As[flat * 8]);
            gl_lds16(Bt + (size_t)(n0 + row) * Kd + k0 + cb * 8, &Bs[flat * 8]);
        }
        __syncthreads();
        for (int kk = 0; kk < 2; ++kk) {
            s16x8 af[4], bf[4];
            for (int i = 0; i < 4; ++i) {
                int ra = wm + i * 16 + lrow;
                int rb = wn + i * 16 + lrow;
                int pba = ((kk * 4 + quad) ^ (ra & 7)) * 8;
                int pbb = ((kk * 4 + quad) ^ (rb & 7)) * 8;
                af[i] = *(const s16x8*)&As[ra * 64 + pba];
                bf[i] = *(const s16x8*)&Bs[rb * 64 + pbb];
            }
            for (int i = 0; i < 4; ++i)
                for (int j = 0; j < 4; ++j)
                    acc[i][j] = __builtin_amdgcn_mfma_f32_16x16x32_bf16(af[i], bf[j],
                                                                        acc[i][j], 0, 0, 0);
        }
    }
    for (int i = 0; i < 4; ++i)
        for (int j = 0; j < 4; ++j)
            for (int r = 0; r < 4; ++r) {
                int m = m0 + wm + i * 16 + quad * 4 + r;
                int n = n0 + wn + j * 16 + lrow;
                if (OUT_F32)
                    ((float*)Cp)[(size_t)m * N + n] = acc[i][j][r];
                else
                    ((__hip_bfloat16*)Cp)[(size_t)m * N + n] = f2b(acc[i][j][r]);
            }
}

// ---------------- RoPE + reshape (q, k only), vectorized ----------------
// Q is pre-scaled by softmax_scale * log2(e) so attention runs in the exp2 domain
// with no per-score multiply. K is unscaled. (Verified R9-R17: absmax unchanged.)
#define QSC 0.12751744f /* (1/sqrt(128)) * 1.4426950408889634 */
__global__ void rope_reshape(const __hip_bfloat16* __restrict__ qkv,
                             const float* __restrict__ fcos, const float* __restrict__ fsin,
                             __hip_bfloat16* __restrict__ q, __hip_bfloat16* __restrict__ k) {
    int tok = blockIdx.x; // b*SEQ + s
    int b = tok >> 11, s = tok & 2047;
    const __hip_bfloat16* row = qkv + (size_t)tok * 3072;
    for (int it = threadIdx.x; it < 320; it += 256) { // 2560 elems / 8
        int col = it * 8;
        s16x8 v = *(const s16x8*)(row + col);
        int p0 = (col & 127) >> 1;
        f32x4 c4 = *(const f32x4*)(fcos + s * 64 + p0);
        f32x4 s4 = *(const f32x4*)(fsin + s * 64 + p0);
        float scl = (col < 2048) ? QSC : 1.0f;
        short outv[8];
        for (int p = 0; p < 4; ++p) {
            float x0 = b2f_us((unsigned short)v[2 * p]);
            float x1 = b2f_us((unsigned short)v[2 * p + 1]);
            outv[2 * p] = f2b_s((x0 * c4[p] - x1 * s4[p]) * scl);
            outv[2 * p + 1] = f2b_s((x0 * s4[p] + x1 * c4[p]) * scl);
        }
        int d = col & 127;
        if (col < 2048) {
            int h = col >> 7;
            *(s16x8*)(q + ((size_t)((b * NH + h) * SEQ + s)) * HD + d) = *(s16x8*)outv;
        } else {
            int h = (col - 2048) >> 7;
            *(s16x8*)(k + ((size_t)((b * NKV + h) * SEQ + s)) * HD + d) = *(s16x8*)outv;
        }
    }
}

// ---------------- V transpose via LDS: qkv v-cols -> vt[b][kv][d][s] ----------------
__global__ void vtrans(const __hip_bfloat16* __restrict__ qkv, __hip_bfloat16* __restrict__ vt) {
    __shared__ __hip_bfloat16 tile[128][136];
    int s0 = blockIdx.x * 128;
    int bh = blockIdx.y; // b*NKV + kvh
    int b = bh >> 2, kvh = bh & 3;
    int t = threadIdx.x;
    for (int i = 0; i < 8; ++i) {
        int flat = (i * 256 + t) * 8;
        int row = flat >> 7, col = flat & 127;
        *(s16x8*)&tile[row][col] =
            *(const s16x8*)(qkv + (size_t)(b * SEQ + s0 + row) * 3072 + 2560 + kvh * 128 + col);
    }
    __syncthreads();
    for (int i = 0; i < 8; ++i) {
        int dd = i * 16 + (t >> 4);
        int ss = (t & 15) * 8;
        __hip_bfloat16 tmp[8];
        for (int j = 0; j < 8; ++j) tmp[j] = tile[ss + j][dd];
        *(s16x8*)(vt + ((size_t)((b * NKV + kvh) * HD + dd)) * SEQ + s0 + ss) = *(s16x8*)tmp;
    }
}

// ---------------- causal flash attention (GQA), 128 q-rows / 512 threads ----------------
// Measured-best attn (R11/R13 structure, 77-81us): no Ps LDS round-trip (V key-column
// posOf permute lets P feed PV straight from regs), K/V double-buffered (one barrier
// per tile steady-state), reg-staged K/V, exp2-domain softmax on pre-scaled Q,
// defer-max (T13), setprio around MFMA clusters, anti-correlated q-tile mapping
// (co-resident block pairs sum to 34 steps). Eight structural variants (R8-R17:
// Ps-removal, dbuf, 64-row/4-wave, K-direct-global, single-buffer, 32x32 MFMA,
// K-split) all measured neutral-to-worse; this is the plateau configuration.
__global__ __launch_bounds__(512, 4) void attn_kernel(
    const __hip_bfloat16* __restrict__ q, const __hip_bfloat16* __restrict__ k,
    const __hip_bfloat16* __restrict__ vt, __hip_bfloat16* __restrict__ o) {
    __shared__ __hip_bfloat16 Ks[2][64][136];  // keys x d, double-buffered
    __shared__ __hip_bfloat16 Vs[2][128][72];  // d x keys (key columns permuted by posOf)

    const int bh = blockIdx.y;
    const int bx = (bh < 16) ? (int)(gridDim.x - 1 - blockIdx.x) : (int)blockIdx.x;
    const int b = bh >> 4, h = bh & 15;
    const int kvh = h >> 2;
    const int t = threadIdx.x;
    const int w = t >> 6, lane = t & 63;
    const int lrow = lane & 15, quad = lane >> 4;
    const int q0 = bx * 128;
    const int qrow = q0 + w * 16 + lrow; // this lane's ONE q row (n-dim)

    // Q fragments, B-operand role: n=qrow (lrow), k=d (quad*8+j). Pre-scaled in rope.
    const __hip_bfloat16* qp = q + ((size_t)((b * NH + h) * SEQ + qrow)) * HD;
    s16x8 qf[4];
    for (int ks = 0; ks < 4; ++ks) qf[ks] = *(const s16x8*)(qp + ks * 32 + quad * 8);

    float m_i = -1e30f, l_i = 0.f;
    f32x4 accO[8];
    f32x4 z4 = {0.f, 0.f, 0.f, 0.f};
    for (int d = 0; d < 8; ++d) accO[d] = z4;

    const __hip_bfloat16* kbase = k + ((size_t)(b * NKV + kvh) * SEQ) * HD;
    const __hip_bfloat16* vbase = vt + ((size_t)(b * NKV + kvh) * HD) * SEQ;

    s16x8 kr[2], vr[2];
    auto load_tile = [&](int kt) {
        for (int i = 0; i < 2; ++i) {
            int flat = (i * 512 + t) * 8;
            kr[i] = *(const s16x8*)(kbase + (size_t)(kt * 64 + (flat >> 7)) * HD + (flat & 127));
            vr[i] = *(const s16x8*)(vbase + (size_t)(flat >> 6) * SEQ + kt * 64 + (flat & 63));
        }
    };
    auto store_tile = [&](int bsel) {
        for (int i = 0; i < 2; ++i) {
            int flat = (i * 512 + t) * 8;
            *(s16x8*)&Ks[bsel][flat >> 7][flat & 127] = kr[i];
            // V: permuted key columns. Lane holds keys k0..k0+7 (k0 = 8-aligned);
            // they land at posOf base..base+3 and base+8..base+11.
            int row = flat >> 6, k0 = flat & 63;
            int pb = ((k0 >> 5) << 5) | (((k0 >> 2) & 2) << 3) | (((k0 >> 4) & 1) << 2);
            s16x4 lo = {vr[i][0], vr[i][1], vr[i][2], vr[i][3]};
            s16x4 hi = {vr[i][4], vr[i][5], vr[i][6], vr[i][7]};
            *(s16x4*)&Vs[bsel][row][pb] = lo;
            *(s16x4*)&Vs[bsel][row][pb + 8] = hi;
        }
    };

    const int nkt = 2 * bx + 2; // keys [0, q0+128)
    load_tile(0);
    store_tile(0);

    for (int kt = 0; kt < nkt; ++kt) {
        const int cur = kt & 1;
        bool more = (kt + 1) < nkt;
        __syncthreads(); // buf[cur] ready (stored last iter / prologue)
        if (more) load_tile(kt + 1); // global->reg, hidden under compute
        bool wave_active = (kt * 64 <= q0 + w * 16 + 15);
        bool mtile = (kt >= 2 * bx); // tile may touch the diagonal

        if (wave_active) {
            float sv[4][4];
            __builtin_amdgcn_s_setprio(1);
            for (int nt = 0; nt < 4; ++nt) {
                f32x4 sacc = z4;
                for (int ks = 0; ks < 4; ++ks) {
                    s16x8 kf = *(const s16x8*)&Ks[cur][nt * 16 + lrow][ks * 32 + quad * 8];
                    sacc = __builtin_amdgcn_mfma_f32_16x16x32_bf16(kf, qf[ks], sacc, 0, 0, 0);
                }
                if (mtile) {
                    for (int r = 0; r < 4; ++r) {
                        int key = kt * 64 + nt * 16 + quad * 4 + r;
                        sv[nt][r] = (key > qrow) ? -1e30f : sacc[r];
                    }
                } else {
                    for (int r = 0; r < 4; ++r) sv[nt][r] = sacc[r];
                }
            }
            __builtin_amdgcn_s_setprio(0);
            float mt2 = fmaxf(fmaxf(fmaxf(sv[0][0], sv[0][1]), fmaxf(sv[0][2], sv[0][3])),
                              fmaxf(fmaxf(sv[1][0], sv[1][1]), fmaxf(sv[1][2], sv[1][3])));
            mt2 = fmaxf(mt2,
                        fmaxf(fmaxf(fmaxf(sv[2][0], sv[2][1]), fmaxf(sv[2][2], sv[2][3])),
                              fmaxf(fmaxf(sv[3][0], sv[3][1]), fmaxf(sv[3][2], sv[3][3]))));
            mt2 = fmaxf(mt2, __shfl_xor(mt2, 16, 64));
            mt2 = fmaxf(mt2, __shfl_xor(mt2, 32, 64));
            // defer-max: only rescale when the running max grew by >8 (exp2 domain,
            // deferred p bounded by 2^8 -- safe in f32/bf16).
            if (!__all(mt2 <= m_i + 8.f)) {
                float mn = fmaxf(m_i, mt2);
                float alpha = exp2f(m_i - mn);
                l_i *= alpha;
                for (int d = 0; d < 8; ++d)
                    for (int r = 0; r < 4; ++r) accO[d][r] *= alpha;
                m_i = mn;
            }
            // P built fully in-register; k-slot (quad,j) of PV mfma#0 is permuted
            // position quad*8+j  <->  key (j>>2)*16 + quad*4 + (j&3) = sv[j>>2][j&3].
            float rs = 0.f;
            s16x8 pf0, pf1;
#pragma unroll
            for (int j = 0; j < 8; ++j) {
                float p0 = exp2f(sv[j >> 2][j & 3] - m_i);
                float p1 = exp2f(sv[2 + (j >> 2)][j & 3] - m_i);
                rs += p0 + p1;
                pf0[j] = f2b_s(p0);
                pf1[j] = f2b_s(p1);
            }
            rs += __shfl_xor(rs, 16, 64);
            rs += __shfl_xor(rs, 32, 64);
            l_i += rs;
            __builtin_amdgcn_s_setprio(1);
            for (int dt = 0; dt < 8; ++dt) {
                s16x8 vf0 = *(const s16x8*)&Vs[cur][dt * 16 + lrow][quad * 8];
                s16x8 vf1 = *(const s16x8*)&Vs[cur][dt * 16 + lrow][32 + quad * 8];
                accO[dt] = __builtin_amdgcn_mfma_f32_16x16x32_bf16(vf0, pf0, accO[dt], 0, 0, 0);
                accO[dt] = __builtin_amdgcn_mfma_f32_16x16x32_bf16(vf1, pf1, accO[dt], 0, 0, 0);
            }
            __builtin_amdgcn_s_setprio(0);
        }

        if (more) store_tile(1 - cur); // write buffer nobody reads this iter
    }
    float inv = 1.0f / l_i;
    __hip_bfloat16* op = o + (size_t)(b * SEQ + qrow) * DM + h * HD;
    for (int dt = 0; dt < 8; ++dt) {
        short ov[4];
        for (int r = 0; r < 4; ++r) ov[r] = f2b_s(accO[dt][r] * inv);
        *(s16x4*)(op + dt * 16 + quad * 4) = *(s16x4*)ov;
    }
}

extern "C" void kernel_launch(void* const* d_in, const int* in_sizes, int n_in,
                              void* d_out, int out_size, void* d_ws, size_t ws_size,
                              hipStream_t stream) {
    (void)in_sizes; (void)n_in; (void)out_size; (void)ws_size;
    const float* x  = (const float*)d_in[0];
    const float* fc = (const float*)d_in[1];
    const float* fs = (const float*)d_in[2];
    // d_in[3] = mask: exactly causal, applied analytically
    const float* wq = (const float*)d_in[4];
    const float* wk = (const float*)d_in[5];
    const float* wv = (const float*)d_in[6];
    const float* wo = (const float*)d_in[7];

    __hip_bfloat16* xb    = (__hip_bfloat16*)d_ws;            // [4096][2048]
    __hip_bfloat16* wqkvt = xb + (size_t)8388608;             // [3072][2048]
    __hip_bfloat16* wot   = wqkvt + (size_t)6291456;          // [2048][2048]
    __hip_bfloat16* qkv   = wot + (size_t)4194304;            // [4096][3072]
    __hip_bfloat16* qb    = xb;                               // aliases xb
    __hip_bfloat16* kb    = wqkvt;                            // aliases wqkvt
    __hip_bfloat16* vtb   = wqkvt + (size_t)2097152;
    __hip_bfloat16* attno = qkv;                              // aliases qkv

    cast_kernel<<<8192, 256, 0, stream>>>(x, xb, 8388608);
    transpose_cast<<<dim3(64, 64), dim3(32, 8), 0, stream>>>(wq, wqkvt, 2048, 2048);
    transpose_cast<<<dim3(16, 64), dim3(32, 8), 0, stream>>>(wk, wqkvt + (size_t)2048 * 2048, 2048, 512);
    transpose_cast<<<dim3(16, 64), dim3(32, 8), 0, stream>>>(wv, wqkvt + (size_t)2560 * 2048, 2048, 512);
    transpose_cast<<<dim3(64, 64), dim3(32, 8), 0, stream>>>(wo, wot, 2048, 2048);
    gemm_bt<0><<<dim3(24, 32), 256, 0, stream>>>(xb, wqkvt, qkv, 4096, 3072, 2048);
    rope_reshape<<<4096, 256, 0, stream>>>(qkv, fc, fs, qb, kb);
    vtrans<<<dim3(16, 8), 256, 0, stream>>>(qkv, vtb);
    attn_kernel<<<dim3(16, 32), 512, 0, stream>>>(qb, kb, vtb, attno);
    gemm_bt<1><<<dim3(16, 32), 256, 0, stream>>>(attno, wot, d_out, 4096, 2048, 2048);
}